// Round 3
// baseline (2740.924 us; speedup 1.0000x reference)
//
#include <hip/hip_runtime.h>
#include <hip/hip_bf16.h>

#define N_NODES 50000
#define N_EDGES 800000
#define D 128
#define BN_EPS 1e-5f
#define GEMM_ROWS 128
#define LDS_PITCH 136                          // 128 + 8 bf16 pad

#define BSH 8                                  // bucket = dst >> 8
#define NB 196                                 // ceil(50000/256) buckets
#define TILE 4096                              // edges per tile
#define NTILES ((N_EDGES + TILE - 1) / TILE)   // 196
#define REC_CAP 6144                           // max records/bucket (mean 4082, sigma 64)
#define CSR_CHUNKS (REC_CAP / 256)             // 24

typedef unsigned short u16;
typedef short bf16x8 __attribute__((ext_vector_type(8)));
typedef float f32x4  __attribute__((ext_vector_type(4)));

__device__ __forceinline__ u16 f2bf(float f) {
    union { float f; unsigned int u; } v; v.f = f;
    unsigned int u = v.u;
    return (u16)((u + 0x7FFF + ((u >> 16) & 1)) >> 16);   // RNE
}
__device__ __forceinline__ float bflo(unsigned int u) {
    union { unsigned int u; float f; } v; v.u = u << 16; return v.f;
}
__device__ __forceinline__ float bfhi(unsigned int u) {
    union { unsigned int u; float f; } v; v.u = u & 0xFFFF0000u; return v.f;
}
__device__ __forceinline__ unsigned int packbf(float a, float b) {
    return (unsigned int)f2bf(a) | ((unsigned int)f2bf(b) << 16);
}

// ---------------------------------------------------------------------------
// kernel 1: per-tile bucket histograms (blocks 0..195) + w_prep (blocks 196..323)
// block 196 also zeros both BN sums banks (layer1 + layer2).
__global__ __launch_bounds__(256) void hist_prep(const int* __restrict__ dst,
                                                 const float* __restrict__ W1,
                                                 const float* __restrict__ W2,
                                                 int* __restrict__ thist,
                                                 u16* __restrict__ Wt1,
                                                 u16* __restrict__ Wt2,
                                                 float* __restrict__ sums) {
    __shared__ int h[256];
    const int t = threadIdx.x;
    const int b = blockIdx.x;
    if (b < NTILES) {
        h[t] = 0;
        __syncthreads();
        const int e0 = b * TILE;
#pragma unroll
        for (int i = 0; i < 16; ++i) {
            int e = e0 + t + 256 * i;
            if (e < N_EDGES) atomicAdd(&h[dst[e] >> BSH], 1);
        }
        __syncthreads();
        thist[b * 256 + t] = h[t];          // all 256 entries written
    } else {
        const int wb = b - NTILES;          // 0..127
        if (wb == 0) { sums[t] = 0.f; sums[256 + t] = 0.f; }
        int u = wb * 256 + t;               // 0..32767
        const float* W = (u < 16384) ? W1 : W2;
        u16* Wt        = (u < 16384) ? Wt1 : Wt2;
        int v = u & 16383;
        int k = v >> 7, n = v & 127;
        Wt[n * 128 + k] = f2bf(W[v]);       // Wt[n][k] = bf16(W[k][n])
    }
}

// ---------------------------------------------------------------------------
// GEMM body: C_bf16[N x 128] = act(X) @ W  (NO dinv here — applied in pull_agg)
template <bool BN_IN>
__device__ __forceinline__ void gemm_body(const void* __restrict__ Xv,
                                          const u16* __restrict__ Wt,
                                          u16* __restrict__ C,
                                          const float* __restrict__ sums,
                                          const float* __restrict__ gamma,
                                          const float* __restrict__ beta,
                                          const float* __restrict__ a,
                                          int nrows, int row0,
                                          u16* __restrict__ As,
                                          u16* __restrict__ Ws) {
    const int tid  = threadIdx.x;
    const float invN = 1.0f / (float)N_NODES;

    const bf16x8* Wt8 = (const bf16x8*)Wt;
#pragma unroll
    for (int i = 0; i < 8; ++i) {
        int u = tid + 256 * i;
        int n = u >> 4, kg = u & 15;
        *(bf16x8*)&Ws[n * LDS_PITCH + kg * 8] = Wt8[u];
    }

    if (BN_IN) {
        const uint4* X4 = (const uint4*)Xv;
        const float av = a[0];
#pragma unroll
        for (int i = 0; i < 8; ++i) {
            int u    = tid + 256 * i;
            int r    = u >> 4, kg = u & 15;
            int grow = row0 + r;
            uint4 o = make_uint4(0, 0, 0, 0);
            if (grow < nrows) {
                uint4 v = X4[(size_t)grow * 16 + kg];
                float f[8] = { bflo(v.x), bfhi(v.x), bflo(v.y), bfhi(v.y),
                               bflo(v.z), bfhi(v.z), bflo(v.w), bfhi(v.w) };
#pragma unroll
                for (int c = 0; c < 8; ++c) {
                    int fe     = kg * 8 + c;
                    float mean = sums[fe] * invN;
                    float var  = sums[128 + fe] * invN - mean * mean;
                    float sc   = rsqrtf(var + BN_EPS) * gamma[fe];
                    float y    = (f[c] - mean) * sc + beta[fe];
                    f[c]       = (y >= 0.f) ? y : av * y;
                }
                o.x = packbf(f[0], f[1]); o.y = packbf(f[2], f[3]);
                o.z = packbf(f[4], f[5]); o.w = packbf(f[6], f[7]);
            }
            *(uint4*)&As[r * LDS_PITCH + kg * 8] = o;
        }
    } else {
        const float4* X4 = (const float4*)Xv;
#pragma unroll
        for (int i = 0; i < 16; ++i) {
            int u    = tid + 256 * i;
            int r    = u >> 5, kf = u & 31;
            int grow = row0 + r;
            float4 v = make_float4(0.f, 0.f, 0.f, 0.f);
            if (grow < nrows) v = X4[(size_t)grow * 32 + kf];
            ushort4 p;
            p.x = f2bf(v.x); p.y = f2bf(v.y); p.z = f2bf(v.z); p.w = f2bf(v.w);
            *(ushort4*)&As[r * LDS_PITCH + kf * 4] = p;
        }
    }
    __syncthreads();

    const int wv   = tid >> 6;
    const int lane = tid & 63;
    const int n    = lane & 15;
    const int q    = lane >> 4;
    const int c0   = wv * 32;

    bf16x8 bfr[4][2];
#pragma unroll
    for (int kb = 0; kb < 4; ++kb)
#pragma unroll
        for (int c = 0; c < 2; ++c)
            bfr[kb][c] = *(const bf16x8*)&Ws[(c0 + 16 * c + n) * LDS_PITCH + 32 * kb + 8 * q];

    f32x4 acc[8][2];
    const f32x4 z = {0.f, 0.f, 0.f, 0.f};
#pragma unroll
    for (int rt = 0; rt < 8; ++rt) { acc[rt][0] = z; acc[rt][1] = z; }

#pragma unroll
    for (int kb = 0; kb < 4; ++kb) {
#pragma unroll
        for (int rt = 0; rt < 8; ++rt) {
            bf16x8 af = *(const bf16x8*)&As[(16 * rt + n) * LDS_PITCH + 32 * kb + 8 * q];
            acc[rt][0] = __builtin_amdgcn_mfma_f32_16x16x32_bf16(af, bfr[kb][0], acc[rt][0], 0, 0, 0);
            acc[rt][1] = __builtin_amdgcn_mfma_f32_16x16x32_bf16(af, bfr[kb][1], acc[rt][1], 0, 0, 0);
        }
    }

#pragma unroll
    for (int rt = 0; rt < 8; ++rt) {
        int gr0 = row0 + 16 * rt + 4 * q;
#pragma unroll
        for (int r = 0; r < 4; ++r) {
            int gr = gr0 + r;
            if (gr < nrows) {
                C[(size_t)gr * D + c0 + n]      = f2bf(acc[rt][0][r]);
                C[(size_t)gr * D + c0 + 16 + n] = f2bf(acc[rt][1][r]);
            }
        }
    }
}

// ---------------------------------------------------------------------------
// Deterministic same-key lane-group mask: 8-bit match-any via 8 ballots.
// All lanes must execute (uniform control flow); invalid lanes excluded via vm.
__device__ __forceinline__ unsigned long long match8(int key, bool valid) {
    unsigned long long vm = __ballot(valid ? 1 : 0);
    unsigned long long m  = ~0ull;
#pragma unroll
    for (int bit = 0; bit < 8; ++bit) {
        unsigned long long vb = __ballot((key >> bit) & 1);
        m &= ((key >> bit) & 1) ? vb : ~vb;
    }
    return m & vm;
}

// ---------------------------------------------------------------------------
// kernel 2 (fused): blocks [0,NTILES) = bucket scatter, blocks [NTILES,..) = GEMM1.
// Scatter is BIT-DETERMINISTIC: ballot-rank position allocation (no LDS-atomic
// order dependence) + thist-derived global bases (bucket_scan kernel deleted;
// last tile publishes btot/bbase/row_ptr[N]).
__global__ __launch_bounds__(256) void scatter_gemm1(const int* __restrict__ src,
                                                     const int* __restrict__ dst,
                                                     const int* __restrict__ thist,
                                                     unsigned int* __restrict__ brec,
                                                     int* __restrict__ btot,
                                                     int* __restrict__ bbase,
                                                     int* __restrict__ row_ptr,
                                                     const float* __restrict__ x,
                                                     const u16* __restrict__ Wt1,
                                                     u16* __restrict__ C) {
    __shared__ __align__(16) u16 smem[2 * 128 * LDS_PITCH];   // 69632 B (union)

    if (blockIdx.x >= NTILES) {
        gemm_body<false>(x, Wt1, C, nullptr, nullptr, nullptr, nullptr,
                         N_NODES, (int)(blockIdx.x - NTILES) * GEMM_ROWS,
                         smem, smem + 128 * LDS_PITCH);
        return;
    }

    // ---- scatter path, carved out of the same LDS ----
    int* wcnt  = (int*)smem;                              // 4*256 per-wave counters
    int* sb    = wcnt + 4 * 256;                          // 256
    int* lbase = sb + 256;                                // 256
    int* gbase = lbase + 256;                             // 256
    unsigned int*  rec = (unsigned int*)(gbase + 256);    // TILE
    unsigned char* rbk = (unsigned char*)(rec + TILE);    // TILE

    const int tile = blockIdx.x;
    const int t    = threadIdx.x;
    const int lane = t & 63;
    const int w    = t >> 6;
    const int e0   = tile * TILE;
    const int tcount = min(TILE, N_EDGES - e0);
    const unsigned long long lt = (1ull << lane) - 1ull;

    wcnt[t] = 0; wcnt[256 + t] = 0; wcnt[512 + t] = 0; wcnt[768 + t] = 0;
    __syncthreads();

    unsigned int myrec[16];
    int          myb[16];
    int          myrank[16];
#pragma unroll
    for (int i = 0; i < 16; ++i) {
        int e = e0 + t + 256 * i;
        bool valid = (e < N_EDGES);
        unsigned int s_ = 0, d_ = 0;
        if (valid) { s_ = (unsigned int)src[e]; d_ = (unsigned int)dst[e]; }
        int b = valid ? (int)(d_ >> BSH) : 0;
        myb[i]   = valid ? b : -1;
        myrec[i] = s_ | ((d_ & 255u) << 16);
        unsigned long long m = match8(b, valid);
        int pre  = __popcll(m & lt);
        int base = wcnt[w * 256 + b];        // own-wave counter: in-order, race-free
        myrank[i] = base + pre;
        if (valid && pre == 0) wcnt[w * 256 + b] = base + __popcll(m);
    }
    __syncthreads();

    // per-bucket totals + fixed wave offsets (thread t = bucket t; column-private)
    int c0 = wcnt[t], c1 = wcnt[256 + t], c2 = wcnt[512 + t], c3 = wcnt[768 + t];
    int tot_l = c0 + c1 + c2 + c3;
    wcnt[t] = 0; wcnt[256 + t] = c0; wcnt[512 + t] = c0 + c1; wcnt[768 + t] = c0 + c1 + c2;
    sb[t] = tot_l;
    __syncthreads();
#pragma unroll
    for (int off = 1; off < 256; off <<= 1) {
        int add = (t >= off) ? sb[t - off] : 0;
        __syncthreads();
        sb[t] += add;
        __syncthreads();
    }
    lbase[t] = sb[t] - tot_l;
    __syncthreads();

    // pass 2: deterministic placement
#pragma unroll
    for (int i = 0; i < 16; ++i) {
        if (myb[i] >= 0) {
            int p = lbase[myb[i]] + wcnt[w * 256 + myb[i]] + myrank[i];
            rec[p] = myrec[i];
            rbk[p] = (unsigned char)myb[i];
        }
    }

    // deterministic global bases: bucket total + prefix over earlier tiles
    int tot = 0, pre = 0;
    for (int j = 0; j < NTILES; ++j) {
        int v = thist[j * 256 + t];
        tot += v;
        if (j < tile) pre += v;
    }
    __syncthreads();   // rec/rbk fill done; sb free for reuse
    sb[t] = tot;
    __syncthreads();
#pragma unroll
    for (int off = 1; off < 256; off <<= 1) {
        int add = (t >= off) ? sb[t - off] : 0;
        __syncthreads();
        sb[t] += add;
        __syncthreads();
    }
    int bb = sb[t] - tot;        // global exclusive bucket base
    gbase[t] = bb + pre;         // this tile's slot inside bucket t
    if (tile == NTILES - 1) {    // all thist is final; any single tile may publish
        btot[t]  = tot;
        bbase[t] = bb;
        if (t == 0) row_ptr[N_NODES] = N_EDGES;
    }
    __syncthreads();

    for (int i = t; i < tcount; i += 256) {
        int b = rbk[i];
        brec[gbase[b] + (i - lbase[b])] = rec[i];
    }
}

// ---------------------------------------------------------------------------
// kernel 3: per-bucket counting sort -> row_ptr, dinv, col (u16).
// BIT-DETERMINISTIC class sort via the same ballot-rank technique.
__global__ __launch_bounds__(256) void bucket_csr(const unsigned int* __restrict__ brec,
                                                  const int* __restrict__ bbase,
                                                  const int* __restrict__ btot,
                                                  int* __restrict__ row_ptr,
                                                  u16* __restrict__ col,
                                                  float* __restrict__ dinv) {
    __shared__ unsigned int rec[REC_CAP];
    __shared__ u16 cls[REC_CAP];
    __shared__ int wcnt[4 * 256];
    __shared__ int sb[256];
    __shared__ int lb[256];
    const int b    = blockIdx.x;
    const int t    = threadIdx.x;
    const int lane = t & 63;
    const int w    = t >> 6;
    const int base = bbase[b];
    const int cnt  = min(btot[b], REC_CAP);
    const int n0   = b << BSH;
    const int nn   = min(256, N_NODES - n0);
    const unsigned long long lt = (1ull << lane) - 1ull;

    for (int i = t; i < cnt; i += 256) rec[i] = brec[base + i];
    wcnt[t] = 0; wcnt[256 + t] = 0; wcnt[512 + t] = 0; wcnt[768 + t] = 0;
    __syncthreads();

    int myrank[CSR_CHUNKS];
#pragma unroll
    for (int kk = 0; kk < CSR_CHUNKS; ++kk) {
        int i = t + 256 * kk;
        bool valid = (i < cnt);
        int c = valid ? (int)((rec[i] >> 16) & 255u) : 0;
        unsigned long long m = match8(c, valid);
        int pre  = __popcll(m & lt);
        int bs_  = wcnt[w * 256 + c];
        myrank[kk] = bs_ + pre;
        if (valid && pre == 0) wcnt[w * 256 + c] = bs_ + __popcll(m);
    }
    __syncthreads();

    int c0 = wcnt[t], c1 = wcnt[256 + t], c2 = wcnt[512 + t], c3 = wcnt[768 + t];
    int tot = c0 + c1 + c2 + c3;            // degree of node n0+t (no self-loop)
    wcnt[t] = 0; wcnt[256 + t] = c0; wcnt[512 + t] = c0 + c1; wcnt[768 + t] = c0 + c1 + c2;
    sb[t] = tot;
    __syncthreads();
#pragma unroll
    for (int off = 1; off < 256; off <<= 1) {
        int add = (t >= off) ? sb[t - off] : 0;
        __syncthreads();
        sb[t] += add;
        __syncthreads();
    }
    int excl = sb[t] - tot;
    lb[t] = excl;
    if (t < nn) {
        row_ptr[n0 + t] = base + excl;
        dinv[n0 + t]    = rsqrtf((float)tot + 1.0f);
    }
    __syncthreads();

#pragma unroll
    for (int kk = 0; kk < CSR_CHUNKS; ++kk) {
        int i = t + 256 * kk;
        if (i < cnt) {
            unsigned int r = rec[i];
            int c = (int)((r >> 16) & 255u);
            int p = lb[c] + wcnt[w * 256 + c] + myrank[kk];
            cls[p] = (u16)(r & 0xFFFFu);
        }
    }
    __syncthreads();
    for (int i = t; i < cnt; i += 256) col[base + i] = cls[i];
}

// ---------------------------------------------------------------------------
// layer-2 GEMM wrapper (BN1+PReLU fused in staging)
__global__ __launch_bounds__(256) void gemm2_k(const u16* __restrict__ Obf,
                                               const u16* __restrict__ Wt2,
                                               u16* __restrict__ C,
                                               const float* __restrict__ sums,
                                               const float* __restrict__ gamma,
                                               const float* __restrict__ beta,
                                               const float* __restrict__ a) {
    __shared__ __align__(16) u16 smem[2 * 128 * LDS_PITCH];
    gemm_body<true>(Obf, Wt2, C, sums, gamma, beta, a,
                    N_NODES, (int)blockIdx.x * GEMM_ROWS,
                    smem, smem + 128 * LDS_PITCH);
}

// ---------------------------------------------------------------------------
// pull-aggregate with fused BN reduction (bf16 in / bf16 out, f32 accumulate):
// out[d] = dinv[d] * (Σ_{s in in(d)} dinv[s]*H[s] + dinv[d]*H[d])
// col[] is now bit-deterministic -> per-node sums bit-exact run-to-run.
// BN stats: register accum (fixed node order) -> exact shfl combine -> fixed-
// order LDS combine -> ONE global atomicAdd per (block, slot).
__global__ __launch_bounds__(256) void pull_agg_bn(const u16* __restrict__ H,
                                                   const int* __restrict__ row_ptr,
                                                   const u16* __restrict__ col,
                                                   const float* __restrict__ dinv,
                                                   u16* __restrict__ out,
                                                   float* __restrict__ sums) {
    const int sub  = threadIdx.x & 15;
    const int grp  = (blockIdx.x * blockDim.x + threadIdx.x) >> 4;
    const int ngrp = (gridDim.x * blockDim.x) >> 4;
    const uint4* H4   = (const uint4*)H;
    uint4*       out4 = (uint4*)out;

    float bs[8] = {0.f, 0.f, 0.f, 0.f, 0.f, 0.f, 0.f, 0.f};
    float bq[8] = {0.f, 0.f, 0.f, 0.f, 0.f, 0.f, 0.f, 0.f};

    for (int d = grp; d < N_NODES; d += ngrp) {
        const int beg = row_ptr[d];
        const int end = row_ptr[d + 1];
        const float dv = dinv[d];
        float a0[8], a1[8] = {}, a2[8] = {}, a3[8] = {};
        {
            uint4 v = H4[(size_t)d * 16 + sub];          // self loop: dv*H[d]
            a0[0] = dv * bflo(v.x); a0[1] = dv * bfhi(v.x);
            a0[2] = dv * bflo(v.y); a0[3] = dv * bfhi(v.y);
            a0[4] = dv * bflo(v.z); a0[5] = dv * bfhi(v.z);
            a0[6] = dv * bflo(v.w); a0[7] = dv * bfhi(v.w);
        }
        int j = beg;
        for (; j + 3 < end; j += 4) {
            const int s0 = col[j], s1 = col[j + 1], s2 = col[j + 2], s3 = col[j + 3];
            const float d0 = dinv[s0], d1 = dinv[s1], d2 = dinv[s2], d3 = dinv[s3];
            const uint4 v0 = H4[(size_t)s0 * 16 + sub];
            const uint4 v1 = H4[(size_t)s1 * 16 + sub];
            const uint4 v2 = H4[(size_t)s2 * 16 + sub];
            const uint4 v3 = H4[(size_t)s3 * 16 + sub];
            a0[0] += d0 * bflo(v0.x); a0[1] += d0 * bfhi(v0.x);
            a0[2] += d0 * bflo(v0.y); a0[3] += d0 * bfhi(v0.y);
            a0[4] += d0 * bflo(v0.z); a0[5] += d0 * bfhi(v0.z);
            a0[6] += d0 * bflo(v0.w); a0[7] += d0 * bfhi(v0.w);
            a1[0] += d1 * bflo(v1.x); a1[1] += d1 * bfhi(v1.x);
            a1[2] += d1 * bflo(v1.y); a1[3] += d1 * bfhi(v1.y);
            a1[4] += d1 * bflo(v1.z); a1[5] += d1 * bfhi(v1.z);
            a1[6] += d1 * bflo(v1.w); a1[7] += d1 * bfhi(v1.w);
            a2[0] += d2 * bflo(v2.x); a2[1] += d2 * bfhi(v2.x);
            a2[2] += d2 * bflo(v2.y); a2[3] += d2 * bfhi(v2.y);
            a2[4] += d2 * bflo(v2.z); a2[5] += d2 * bfhi(v2.z);
            a2[6] += d2 * bflo(v2.w); a2[7] += d2 * bfhi(v2.w);
            a3[0] += d3 * bflo(v3.x); a3[1] += d3 * bfhi(v3.x);
            a3[2] += d3 * bflo(v3.y); a3[3] += d3 * bfhi(v3.y);
            a3[4] += d3 * bflo(v3.z); a3[5] += d3 * bfhi(v3.z);
            a3[6] += d3 * bflo(v3.w); a3[7] += d3 * bfhi(v3.w);
        }
        for (; j < end; ++j) {
            const int s0 = col[j];
            const float d0 = dinv[s0];
            const uint4 v = H4[(size_t)s0 * 16 + sub];
            a0[0] += d0 * bflo(v.x); a0[1] += d0 * bfhi(v.x);
            a0[2] += d0 * bflo(v.y); a0[3] += d0 * bfhi(v.y);
            a0[4] += d0 * bflo(v.z); a0[5] += d0 * bfhi(v.z);
            a0[6] += d0 * bflo(v.w); a0[7] += d0 * bfhi(v.w);
        }
        float r[8];
#pragma unroll
        for (int c = 0; c < 8; ++c) r[c] = ((a0[c] + a1[c]) + (a2[c] + a3[c])) * dv;
        uint4 o;
        o.x = packbf(r[0], r[1]); o.y = packbf(r[2], r[3]);
        o.z = packbf(r[4], r[5]); o.w = packbf(r[6], r[7]);
        out4[(size_t)d * 16 + sub] = o;

#pragma unroll
        for (int c = 0; c < 8; ++c) { bs[c] += r[c]; bq[c] += r[c] * r[c]; }
    }

    // exact combine of the 4 groups within each wave (lanes differ by 16/32)
#pragma unroll
    for (int c = 0; c < 8; ++c) {
        bs[c] += __shfl_xor(bs[c], 16, 64);
        bs[c] += __shfl_xor(bs[c], 32, 64);
        bq[c] += __shfl_xor(bq[c], 16, 64);
        bq[c] += __shfl_xor(bq[c], 32, 64);
    }

    __shared__ float ls[4 * 256];   // [wave][sub][16] : 0..7 sum, 8..15 sumsq
    const int lane = threadIdx.x & 63;
    const int wv   = threadIdx.x >> 6;
    if (lane < 16) {
#pragma unroll
        for (int c = 0; c < 8; ++c) {
            ls[wv * 256 + lane * 16 + c]     = bs[c];
            ls[wv * 256 + lane * 16 + 8 + c] = bq[c];
        }
    }
    __syncthreads();

    // tid -> (feature-block s2, slot vi); fixed-order 4-wave combine
    const int s2 = threadIdx.x >> 4;
    const int vi = threadIdx.x & 15;
    float v = ((ls[s2 * 16 + vi] + ls[256 + s2 * 16 + vi]) +
               (ls[512 + s2 * 16 + vi] + ls[768 + s2 * 16 + vi]));
    const int f = s2 * 8 + (vi & 7);
    atomicAdd(&sums[(vi < 8) ? f : (128 + f)], v);
}

// ---------------------------------------------------------------------------
// BN + PReLU, bf16 in -> f32 out (final)
__global__ void bn_prelu_bf(const u16* __restrict__ X, const float* __restrict__ sums,
                            const float* __restrict__ gamma, const float* __restrict__ beta,
                            const float* __restrict__ a, float* __restrict__ out,
                            float invN) {
    int idx = blockIdx.x * blockDim.x + threadIdx.x;     // pair index
    if (idx >= N_NODES * 64) return;
    unsigned int u = ((const unsigned int*)X)[idx];
    int f0 = (idx * 2) & 127;
    float av = a[0];
    float2 o;
    {
        float mean = sums[f0] * invN;
        float var  = sums[128 + f0] * invN - mean * mean;
        float sc   = rsqrtf(var + BN_EPS) * gamma[f0];
        float y    = (bflo(u) - mean) * sc + beta[f0];
        o.x = (y >= 0.f) ? y : av * y;
    }
    {
        int f1 = f0 + 1;
        float mean = sums[f1] * invN;
        float var  = sums[128 + f1] * invN - mean * mean;
        float sc   = rsqrtf(var + BN_EPS) * gamma[f1];
        float y    = (bfhi(u) - mean) * sc + beta[f1];
        o.y = (y >= 0.f) ? y : av * y;
    }
    ((float2*)out)[idx] = o;
}

// ---------------------------------------------------------------------------
extern "C" void kernel_launch(void* const* d_in, const int* in_sizes, int n_in,
                              void* d_out, int out_size, void* d_ws, size_t ws_size,
                              hipStream_t stream) {
    const float* x      = (const float*)d_in[0];
    const int*   edges  = (const int*)d_in[1];   // [2, E]: src then dst
    const float* W1     = (const float*)d_in[2];
    // b1 = d_in[3] cancels under training-mode BN -> skipped
    const float* gamma1 = (const float*)d_in[4];
    const float* beta1  = (const float*)d_in[5];
    const float* a1     = (const float*)d_in[6];
    const float* W2     = (const float*)d_in[7];
    // b2 = d_in[8] skipped (same reason)
    const float* gamma2 = (const float*)d_in[9];
    const float* beta2  = (const float*)d_in[10];
    const float* a2     = (const float*)d_in[11];

    const int* src = edges;
    const int* dst = edges + N_EDGES;

    float* OUT = (float*)d_out;                      // final f32 output
    char* ws = (char*)d_ws;
    u16*   Abf      = (u16*)ws;    ws += (size_t)N_NODES * D * sizeof(u16);   // 12.8 MB
    u16*   Obf      = (u16*)ws;    ws += (size_t)N_NODES * D * sizeof(u16);   // 12.8 MB
    float* dinv     = (float*)ws;  ws += N_NODES * sizeof(float);
    float* sums     = (float*)ws;  ws += 512 * sizeof(float);   // [0..255]=L1, [256..511]=L2
    int*   row_ptr  = (int*)ws;    ws += (N_NODES + 1) * sizeof(int);
    int*   btot     = (int*)ws;    ws += NB * sizeof(int);
    int*   bbase    = (int*)ws;    ws += NB * sizeof(int);
    int*   thist    = (int*)ws;    ws += (size_t)NTILES * 256 * sizeof(int);  // 200 KB
    unsigned int* brec = (unsigned int*)ws; ws += (size_t)N_EDGES * sizeof(unsigned int);
    u16*   col      = (u16*)ws;    ws += (size_t)N_EDGES * sizeof(u16);
    u16*   Wt1      = (u16*)ws;    ws += 16384 * sizeof(u16);
    u16*   Wt2      = (u16*)ws;    ws += 16384 * sizeof(u16);

    const float invN = 1.0f / (float)N_NODES;
    const int gemmGrid = (N_NODES + GEMM_ROWS - 1) / GEMM_ROWS;   // 391
    const int prGrid   = (N_NODES * 64 + 255) / 256;              // 12500

    // --- hist + weight prep + sums zero ---
    hist_prep<<<NTILES + 128, 256, 0, stream>>>(dst, W1, W2, thist, Wt1, Wt2, sums);

    // --- fused: deterministic bucket scatter + GEMM1 ---
    scatter_gemm1<<<NTILES + gemmGrid, 256, 0, stream>>>(src, dst, thist, brec,
                                                         btot, bbase, row_ptr,
                                                         x, Wt1, Abf);
    bucket_csr<<<NB, 256, 0, stream>>>(brec, bbase, btot, row_ptr, col, dinv);

    // --- layer 1 aggregate (+ fused deterministic BN reduce into sums[0..255]) ---
    pull_agg_bn<<<2048, 256, 0, stream>>>(Abf, row_ptr, col, dinv, Obf, sums);

    // --- layer 2 (BN1+PReLU fused into GEMM2 staging) ---
    gemm2_k<<<gemmGrid, 256, 0, stream>>>(Obf, Wt2, Abf, sums, gamma1, beta1, a1);
    pull_agg_bn<<<2048, 256, 0, stream>>>(Abf, row_ptr, col, dinv, Obf, sums + 256);
    bn_prelu_bf<<<prGrid, 256, 0, stream>>>(Obf, sums + 256, gamma2, beta2, a2, OUT, invN);
}

// Round 6
// 299.651 us; speedup vs baseline: 9.1471x; 9.1471x over previous
//
#include <hip/hip_runtime.h>
#include <hip/hip_bf16.h>

#define N_NODES 50000
#define N_EDGES 800000
#define D 128
#define BN_EPS 1e-5f
#define GEMM_ROWS 128
#define LDS_PITCH 136                          // 128 + 8 bf16 pad

#define BSH 8                                  // bucket = dst >> 8
#define NB 196                                 // ceil(50000/256) buckets
#define TILE 4096                              // edges per tile
#define NTILES ((N_EDGES + TILE - 1) / TILE)   // 196
#define REC_CAP 6144                           // max records/bucket (mean 4082, sigma 64)
#define CSR_CHUNKS (REC_CAP / 256)             // 24

typedef unsigned short u16;
typedef short bf16x8 __attribute__((ext_vector_type(8)));
typedef float f32x4  __attribute__((ext_vector_type(4)));

__device__ __forceinline__ u16 f2bf(float f) {
    union { float f; unsigned int u; } v; v.f = f;
    unsigned int u = v.u;
    return (u16)((u + 0x7FFF + ((u >> 16) & 1)) >> 16);   // RNE
}
__device__ __forceinline__ float bflo(unsigned int u) {
    union { unsigned int u; float f; } v; v.u = u << 16; return v.f;
}
__device__ __forceinline__ float bfhi(unsigned int u) {
    union { unsigned int u; float f; } v; v.u = u & 0xFFFF0000u; return v.f;
}
__device__ __forceinline__ unsigned int packbf(float a, float b) {
    return (unsigned int)f2bf(a) | ((unsigned int)f2bf(b) << 16);
}

// ---------------------------------------------------------------------------
// kernel 1: per-tile bucket histograms (blocks 0..195) + w_prep (blocks 196..323)
// block 196 also zeros both BN sums banks (layer1 + layer2).
__global__ __launch_bounds__(256) void hist_prep(const int* __restrict__ dst,
                                                 const float* __restrict__ W1,
                                                 const float* __restrict__ W2,
                                                 int* __restrict__ thist,
                                                 u16* __restrict__ Wt1,
                                                 u16* __restrict__ Wt2,
                                                 float* __restrict__ sums) {
    __shared__ int h[256];
    const int t = threadIdx.x;
    const int b = blockIdx.x;
    if (b < NTILES) {
        h[t] = 0;
        __syncthreads();
        const int e0 = b * TILE;
#pragma unroll
        for (int i = 0; i < 16; ++i) {
            int e = e0 + t + 256 * i;
            if (e < N_EDGES) atomicAdd(&h[dst[e] >> BSH], 1);
        }
        __syncthreads();
        thist[b * 256 + t] = h[t];          // all 256 entries written
    } else {
        const int wb = b - NTILES;          // 0..127
        if (wb == 0) { sums[t] = 0.f; sums[256 + t] = 0.f; }
        int u = wb * 256 + t;               // 0..32767
        const float* W = (u < 16384) ? W1 : W2;
        u16* Wt        = (u < 16384) ? Wt1 : Wt2;
        int v = u & 16383;
        int k = v >> 7, n = v & 127;
        Wt[n * 128 + k] = f2bf(W[v]);       // Wt[n][k] = bf16(W[k][n])
    }
}

// ---------------------------------------------------------------------------
// GEMM body: C_bf16[N x 128] = act(X) @ W  (NO dinv here — applied in pull_agg)
template <bool BN_IN>
__device__ __forceinline__ void gemm_body(const void* __restrict__ Xv,
                                          const u16* __restrict__ Wt,
                                          u16* __restrict__ C,
                                          const float* __restrict__ sums,
                                          const float* __restrict__ gamma,
                                          const float* __restrict__ beta,
                                          const float* __restrict__ a,
                                          int nrows, int row0,
                                          u16* __restrict__ As,
                                          u16* __restrict__ Ws) {
    const int tid  = threadIdx.x;
    const float invN = 1.0f / (float)N_NODES;

    const bf16x8* Wt8 = (const bf16x8*)Wt;
#pragma unroll
    for (int i = 0; i < 8; ++i) {
        int u = tid + 256 * i;
        int n = u >> 4, kg = u & 15;
        *(bf16x8*)&Ws[n * LDS_PITCH + kg * 8] = Wt8[u];
    }

    if (BN_IN) {
        const uint4* X4 = (const uint4*)Xv;
        const float av = a[0];
#pragma unroll
        for (int i = 0; i < 8; ++i) {
            int u    = tid + 256 * i;
            int r    = u >> 4, kg = u & 15;
            int grow = row0 + r;
            uint4 o = make_uint4(0, 0, 0, 0);
            if (grow < nrows) {
                uint4 v = X4[(size_t)grow * 16 + kg];
                float f[8] = { bflo(v.x), bfhi(v.x), bflo(v.y), bfhi(v.y),
                               bflo(v.z), bfhi(v.z), bflo(v.w), bfhi(v.w) };
#pragma unroll
                for (int c = 0; c < 8; ++c) {
                    int fe     = kg * 8 + c;
                    float mean = sums[fe] * invN;
                    float var  = sums[128 + fe] * invN - mean * mean;
                    float sc   = rsqrtf(var + BN_EPS) * gamma[fe];
                    float y    = (f[c] - mean) * sc + beta[fe];
                    f[c]       = (y >= 0.f) ? y : av * y;
                }
                o.x = packbf(f[0], f[1]); o.y = packbf(f[2], f[3]);
                o.z = packbf(f[4], f[5]); o.w = packbf(f[6], f[7]);
            }
            *(uint4*)&As[r * LDS_PITCH + kg * 8] = o;
        }
    } else {
        const float4* X4 = (const float4*)Xv;
#pragma unroll
        for (int i = 0; i < 16; ++i) {
            int u    = tid + 256 * i;
            int r    = u >> 5, kf = u & 31;
            int grow = row0 + r;
            float4 v = make_float4(0.f, 0.f, 0.f, 0.f);
            if (grow < nrows) v = X4[(size_t)grow * 32 + kf];
            ushort4 p;
            p.x = f2bf(v.x); p.y = f2bf(v.y); p.z = f2bf(v.z); p.w = f2bf(v.w);
            *(ushort4*)&As[r * LDS_PITCH + kf * 4] = p;
        }
    }
    __syncthreads();

    const int wv   = tid >> 6;
    const int lane = tid & 63;
    const int n    = lane & 15;
    const int q    = lane >> 4;
    const int c0   = wv * 32;

    bf16x8 bfr[4][2];
#pragma unroll
    for (int kb = 0; kb < 4; ++kb)
#pragma unroll
        for (int c = 0; c < 2; ++c)
            bfr[kb][c] = *(const bf16x8*)&Ws[(c0 + 16 * c + n) * LDS_PITCH + 32 * kb + 8 * q];

    f32x4 acc[8][2];
    const f32x4 z = {0.f, 0.f, 0.f, 0.f};
#pragma unroll
    for (int rt = 0; rt < 8; ++rt) { acc[rt][0] = z; acc[rt][1] = z; }

#pragma unroll
    for (int kb = 0; kb < 4; ++kb) {
#pragma unroll
        for (int rt = 0; rt < 8; ++rt) {
            bf16x8 af = *(const bf16x8*)&As[(16 * rt + n) * LDS_PITCH + 32 * kb + 8 * q];
            acc[rt][0] = __builtin_amdgcn_mfma_f32_16x16x32_bf16(af, bfr[kb][0], acc[rt][0], 0, 0, 0);
            acc[rt][1] = __builtin_amdgcn_mfma_f32_16x16x32_bf16(af, bfr[kb][1], acc[rt][1], 0, 0, 0);
        }
    }

#pragma unroll
    for (int rt = 0; rt < 8; ++rt) {
        int gr0 = row0 + 16 * rt + 4 * q;
#pragma unroll
        for (int r = 0; r < 4; ++r) {
            int gr = gr0 + r;
            if (gr < nrows) {
                C[(size_t)gr * D + c0 + n]      = f2bf(acc[rt][0][r]);
                C[(size_t)gr * D + c0 + 16 + n] = f2bf(acc[rt][1][r]);
            }
        }
    }
}

// ---------------------------------------------------------------------------
// Deterministic same-key lane-group mask: 8-bit match-any via 8 ballots.
__device__ __forceinline__ unsigned long long match8(int key, bool valid) {
    unsigned long long vm = __ballot(valid ? 1 : 0);
    unsigned long long m  = ~0ull;
#pragma unroll
    for (int bit = 0; bit < 8; ++bit) {
        unsigned long long vb = __ballot((key >> bit) & 1);
        m &= ((key >> bit) & 1) ? vb : ~vb;
    }
    return m & vm;
}

// ---------------------------------------------------------------------------
// kernel 2 (fused): blocks [0,NTILES) = bucket scatter, blocks [NTILES,..) = GEMM1.
// Scatter is BIT-DETERMINISTIC: ballot-rank position allocation + thist-derived
// global bases. Publication of btot/bbase GUARDED to t<NB (r1-r5 bug: unguarded
// 256-wide writes overflowed btot->bbase->thist, racing with concurrent readers).
__global__ __launch_bounds__(256) void scatter_gemm1(const int* __restrict__ src,
                                                     const int* __restrict__ dst,
                                                     const int* __restrict__ thist,
                                                     unsigned int* __restrict__ brec,
                                                     int* __restrict__ btot,
                                                     int* __restrict__ bbase,
                                                     int* __restrict__ row_ptr,
                                                     const float* __restrict__ x,
                                                     const u16* __restrict__ Wt1,
                                                     u16* __restrict__ C) {
    __shared__ __align__(16) u16 smem[2 * 128 * LDS_PITCH];   // 69632 B (union)

    if (blockIdx.x >= NTILES) {
        gemm_body<false>(x, Wt1, C, nullptr, nullptr, nullptr, nullptr,
                         N_NODES, (int)(blockIdx.x - NTILES) * GEMM_ROWS,
                         smem, smem + 128 * LDS_PITCH);
        return;
    }

    // ---- scatter path, carved out of the same LDS ----
    int* wcnt  = (int*)smem;                              // 4*256 per-wave counters
    int* sb    = wcnt + 4 * 256;                          // 256
    int* lbase = sb + 256;                                // 256
    int* gbase = lbase + 256;                             // 256
    unsigned int*  rec = (unsigned int*)(gbase + 256);    // TILE
    unsigned char* rbk = (unsigned char*)(rec + TILE);    // TILE

    const int tile = blockIdx.x;
    const int t    = threadIdx.x;
    const int lane = t & 63;
    const int w    = t >> 6;
    const int e0   = tile * TILE;
    const int tcount = min(TILE, N_EDGES - e0);
    const unsigned long long lt = (1ull << lane) - 1ull;

    wcnt[t] = 0; wcnt[256 + t] = 0; wcnt[512 + t] = 0; wcnt[768 + t] = 0;
    __syncthreads();

    unsigned int myrec[16];
    int          myb[16];
    int          myrank[16];
#pragma unroll
    for (int i = 0; i < 16; ++i) {
        int e = e0 + t + 256 * i;
        bool valid = (e < N_EDGES);
        unsigned int s_ = 0, d_ = 0;
        if (valid) { s_ = (unsigned int)src[e]; d_ = (unsigned int)dst[e]; }
        int b = valid ? (int)(d_ >> BSH) : 0;
        myb[i]   = valid ? b : -1;
        myrec[i] = s_ | ((d_ & 255u) << 16);
        unsigned long long m = match8(b, valid);
        int pre  = __popcll(m & lt);
        int base = wcnt[w * 256 + b];        // own-wave counter: in-order, race-free
        myrank[i] = base + pre;
        if (valid && pre == 0) wcnt[w * 256 + b] = base + __popcll(m);
    }
    __syncthreads();

    // per-bucket totals + fixed wave offsets (thread t = bucket t; column-private)
    int c0 = wcnt[t], c1 = wcnt[256 + t], c2 = wcnt[512 + t], c3 = wcnt[768 + t];
    int tot_l = c0 + c1 + c2 + c3;
    wcnt[t] = 0; wcnt[256 + t] = c0; wcnt[512 + t] = c0 + c1; wcnt[768 + t] = c0 + c1 + c2;
    sb[t] = tot_l;
    __syncthreads();
#pragma unroll
    for (int off = 1; off < 256; off <<= 1) {
        int add = (t >= off) ? sb[t - off] : 0;
        __syncthreads();
        sb[t] += add;
        __syncthreads();
    }
    lbase[t] = sb[t] - tot_l;
    __syncthreads();

    // pass 2: deterministic placement
#pragma unroll
    for (int i = 0; i < 16; ++i) {
        if (myb[i] >= 0) {
            int p = lbase[myb[i]] + wcnt[w * 256 + myb[i]] + myrank[i];
            rec[p] = myrec[i];
            rbk[p] = (unsigned char)myb[i];
        }
    }

    // deterministic global bases: bucket total + prefix over earlier tiles
    int tot = 0, pre = 0;
    for (int j = 0; j < NTILES; ++j) {
        int v = thist[j * 256 + t];
        tot += v;
        if (j < tile) pre += v;
    }
    __syncthreads();   // rec/rbk fill done; sb free for reuse
    sb[t] = tot;
    __syncthreads();
#pragma unroll
    for (int off = 1; off < 256; off <<= 1) {
        int add = (t >= off) ? sb[t - off] : 0;
        __syncthreads();
        sb[t] += add;
        __syncthreads();
    }
    int bb = sb[t] - tot;        // global exclusive bucket base
    gbase[t] = bb + pre;         // this tile's slot inside bucket t
    if (tile == NTILES - 1 && t < NB) {   // GUARDED: btot/bbase are NB ints
        btot[t]  = tot;
        bbase[t] = bb;
        if (t == 0) row_ptr[N_NODES] = N_EDGES;
    }
    __syncthreads();

    for (int i = t; i < tcount; i += 256) {
        int b = rbk[i];
        brec[gbase[b] + (i - lbase[b])] = rec[i];
    }
}

// ---------------------------------------------------------------------------
// kernel 3: per-bucket counting sort -> row_ptr, dinv, col (u16).
// BIT-DETERMINISTIC class sort via the same ballot-rank technique.
__global__ __launch_bounds__(256) void bucket_csr(const unsigned int* __restrict__ brec,
                                                  const int* __restrict__ bbase,
                                                  const int* __restrict__ btot,
                                                  int* __restrict__ row_ptr,
                                                  u16* __restrict__ col,
                                                  float* __restrict__ dinv) {
    __shared__ unsigned int rec[REC_CAP];
    __shared__ u16 cls[REC_CAP];
    __shared__ int wcnt[4 * 256];
    __shared__ int sb[256];
    __shared__ int lb[256];
    const int b    = blockIdx.x;
    const int t    = threadIdx.x;
    const int lane = t & 63;
    const int w    = t >> 6;
    const int base = bbase[b];
    const int cnt  = min(btot[b], REC_CAP);
    const int n0   = b << BSH;
    const int nn   = min(256, N_NODES - n0);
    const unsigned long long lt = (1ull << lane) - 1ull;

    for (int i = t; i < cnt; i += 256) rec[i] = brec[base + i];
    wcnt[t] = 0; wcnt[256 + t] = 0; wcnt[512 + t] = 0; wcnt[768 + t] = 0;
    __syncthreads();

    int myrank[CSR_CHUNKS];
#pragma unroll
    for (int kk = 0; kk < CSR_CHUNKS; ++kk) {
        int i = t + 256 * kk;
        bool valid = (i < cnt);
        int c = valid ? (int)((rec[i] >> 16) & 255u) : 0;
        unsigned long long m = match8(c, valid);
        int pre  = __popcll(m & lt);
        int bs_  = wcnt[w * 256 + c];
        myrank[kk] = bs_ + pre;
        if (valid && pre == 0) wcnt[w * 256 + c] = bs_ + __popcll(m);
    }
    __syncthreads();

    int c0 = wcnt[t], c1 = wcnt[256 + t], c2 = wcnt[512 + t], c3 = wcnt[768 + t];
    int tot = c0 + c1 + c2 + c3;            // degree of node n0+t (no self-loop)
    wcnt[t] = 0; wcnt[256 + t] = c0; wcnt[512 + t] = c0 + c1; wcnt[768 + t] = c0 + c1 + c2;
    sb[t] = tot;
    __syncthreads();
#pragma unroll
    for (int off = 1; off < 256; off <<= 1) {
        int add = (t >= off) ? sb[t - off] : 0;
        __syncthreads();
        sb[t] += add;
        __syncthreads();
    }
    int excl = sb[t] - tot;
    lb[t] = excl;
    if (t < nn) {
        row_ptr[n0 + t] = base + excl;
        dinv[n0 + t]    = rsqrtf((float)tot + 1.0f);
    }
    __syncthreads();

#pragma unroll
    for (int kk = 0; kk < CSR_CHUNKS; ++kk) {
        int i = t + 256 * kk;
        if (i < cnt) {
            unsigned int r = rec[i];
            int c = (int)((r >> 16) & 255u);
            int p = lb[c] + wcnt[w * 256 + c] + myrank[kk];
            cls[p] = (u16)(r & 0xFFFFu);
        }
    }
    __syncthreads();
    for (int i = t; i < cnt; i += 256) col[base + i] = cls[i];
}

// ---------------------------------------------------------------------------
// layer-2 GEMM wrapper (BN1+PReLU fused in staging)
__global__ __launch_bounds__(256) void gemm2_k(const u16* __restrict__ Obf,
                                               const u16* __restrict__ Wt2,
                                               u16* __restrict__ C,
                                               const float* __restrict__ sums,
                                               const float* __restrict__ gamma,
                                               const float* __restrict__ beta,
                                               const float* __restrict__ a) {
    __shared__ __align__(16) u16 smem[2 * 128 * LDS_PITCH];
    gemm_body<true>(Obf, Wt2, C, sums, gamma, beta, a,
                    N_NODES, (int)blockIdx.x * GEMM_ROWS,
                    smem, smem + 128 * LDS_PITCH);
}

// ---------------------------------------------------------------------------
// pull-aggregate with fused BN reduction (bf16 in / bf16 out, f32 accumulate):
// out[d] = dinv[d] * (Σ_{s in in(d)} dinv[s]*H[s] + dinv[d]*H[d])
// __launch_bounds__(256, 4): VGPR cap 128 (r3: compiler squeezed to 52 for
// 8-waves/SIMD, serializing the 4 uint4 gathers -> 20x slowdown).
__global__ __launch_bounds__(256, 4) void pull_agg_bn(const u16* __restrict__ H,
                                                      const int* __restrict__ row_ptr,
                                                      const u16* __restrict__ col,
                                                      const float* __restrict__ dinv,
                                                      u16* __restrict__ out,
                                                      float* __restrict__ sums) {
    const int sub  = threadIdx.x & 15;
    const int grp  = (blockIdx.x * blockDim.x + threadIdx.x) >> 4;
    const int ngrp = (gridDim.x * blockDim.x) >> 4;
    const uint4* H4   = (const uint4*)H;
    uint4*       out4 = (uint4*)out;

    float bs[8] = {0.f, 0.f, 0.f, 0.f, 0.f, 0.f, 0.f, 0.f};
    float bq[8] = {0.f, 0.f, 0.f, 0.f, 0.f, 0.f, 0.f, 0.f};

    for (int d = grp; d < N_NODES; d += ngrp) {
        const int beg = row_ptr[d];
        const int end = row_ptr[d + 1];
        const float dv = dinv[d];
        float a0[8], a1[8] = {}, a2[8] = {}, a3[8] = {};
        {
            uint4 v = H4[(size_t)d * 16 + sub];          // self loop: dv*H[d]
            a0[0] = dv * bflo(v.x); a0[1] = dv * bfhi(v.x);
            a0[2] = dv * bflo(v.y); a0[3] = dv * bfhi(v.y);
            a0[4] = dv * bflo(v.z); a0[5] = dv * bfhi(v.z);
            a0[6] = dv * bflo(v.w); a0[7] = dv * bfhi(v.w);
        }
        int j = beg;
        for (; j + 3 < end; j += 4) {
            const int s0 = col[j], s1 = col[j + 1], s2 = col[j + 2], s3 = col[j + 3];
            const float d0 = dinv[s0], d1 = dinv[s1], d2 = dinv[s2], d3 = dinv[s3];
            const uint4 v0 = H4[(size_t)s0 * 16 + sub];
            const uint4 v1 = H4[(size_t)s1 * 16 + sub];
            const uint4 v2 = H4[(size_t)s2 * 16 + sub];
            const uint4 v3 = H4[(size_t)s3 * 16 + sub];
            a0[0] += d0 * bflo(v0.x); a0[1] += d0 * bfhi(v0.x);
            a0[2] += d0 * bflo(v0.y); a0[3] += d0 * bfhi(v0.y);
            a0[4] += d0 * bflo(v0.z); a0[5] += d0 * bfhi(v0.z);
            a0[6] += d0 * bflo(v0.w); a0[7] += d0 * bfhi(v0.w);
            a1[0] += d1 * bflo(v1.x); a1[1] += d1 * bfhi(v1.x);
            a1[2] += d1 * bflo(v1.y); a1[3] += d1 * bfhi(v1.y);
            a1[4] += d1 * bflo(v1.z); a1[5] += d1 * bfhi(v1.z);
            a1[6] += d1 * bflo(v1.w); a1[7] += d1 * bfhi(v1.w);
            a2[0] += d2 * bflo(v2.x); a2[1] += d2 * bfhi(v2.x);
            a2[2] += d2 * bflo(v2.y); a2[3] += d2 * bfhi(v2.y);
            a2[4] += d2 * bflo(v2.z); a2[5] += d2 * bfhi(v2.z);
            a2[6] += d2 * bflo(v2.w); a2[7] += d2 * bfhi(v2.w);
            a3[0] += d3 * bflo(v3.x); a3[1] += d3 * bfhi(v3.x);
            a3[2] += d3 * bflo(v3.y); a3[3] += d3 * bfhi(v3.y);
            a3[4] += d3 * bflo(v3.z); a3[5] += d3 * bfhi(v3.z);
            a3[6] += d3 * bflo(v3.w); a3[7] += d3 * bfhi(v3.w);
        }
        for (; j < end; ++j) {
            const int s0 = col[j];
            const float d0 = dinv[s0];
            const uint4 v = H4[(size_t)s0 * 16 + sub];
            a0[0] += d0 * bflo(v.x); a0[1] += d0 * bfhi(v.x);
            a0[2] += d0 * bflo(v.y); a0[3] += d0 * bfhi(v.y);
            a0[4] += d0 * bflo(v.z); a0[5] += d0 * bfhi(v.z);
            a0[6] += d0 * bflo(v.w); a0[7] += d0 * bfhi(v.w);
        }
        float r[8];
#pragma unroll
        for (int c = 0; c < 8; ++c) r[c] = ((a0[c] + a1[c]) + (a2[c] + a3[c])) * dv;
        uint4 o;
        o.x = packbf(r[0], r[1]); o.y = packbf(r[2], r[3]);
        o.z = packbf(r[4], r[5]); o.w = packbf(r[6], r[7]);
        out4[(size_t)d * 16 + sub] = o;

#pragma unroll
        for (int c = 0; c < 8; ++c) { bs[c] += r[c]; bq[c] += r[c] * r[c]; }
    }

    // exact combine of the 4 groups within each wave (lanes differ by 16/32)
#pragma unroll
    for (int c = 0; c < 8; ++c) {
        bs[c] += __shfl_xor(bs[c], 16, 64);
        bs[c] += __shfl_xor(bs[c], 32, 64);
        bq[c] += __shfl_xor(bq[c], 16, 64);
        bq[c] += __shfl_xor(bq[c], 32, 64);
    }

    __shared__ float ls[4 * 256];   // [wave][sub][16] : 0..7 sum, 8..15 sumsq
    const int lane = threadIdx.x & 63;
    const int wv   = threadIdx.x >> 6;
    if (lane < 16) {
#pragma unroll
        for (int c = 0; c < 8; ++c) {
            ls[wv * 256 + lane * 16 + c]     = bs[c];
            ls[wv * 256 + lane * 16 + 8 + c] = bq[c];
        }
    }
    __syncthreads();

    // tid -> (feature-block s2, slot vi); fixed-order 4-wave combine
    const int s2 = threadIdx.x >> 4;
    const int vi = threadIdx.x & 15;
    float v = ((ls[s2 * 16 + vi] + ls[256 + s2 * 16 + vi]) +
               (ls[512 + s2 * 16 + vi] + ls[768 + s2 * 16 + vi]));
    const int f = s2 * 8 + (vi & 7);
    atomicAdd(&sums[(vi < 8) ? f : (128 + f)], v);
}

// ---------------------------------------------------------------------------
// BN + PReLU, bf16 in -> f32 out (final)
__global__ void bn_prelu_bf(const u16* __restrict__ X, const float* __restrict__ sums,
                            const float* __restrict__ gamma, const float* __restrict__ beta,
                            const float* __restrict__ a, float* __restrict__ out,
                            float invN) {
    int idx = blockIdx.x * blockDim.x + threadIdx.x;     // pair index
    if (idx >= N_NODES * 64) return;
    unsigned int u = ((const unsigned int*)X)[idx];
    int f0 = (idx * 2) & 127;
    float av = a[0];
    float2 o;
    {
        float mean = sums[f0] * invN;
        float var  = sums[128 + f0] * invN - mean * mean;
        float sc   = rsqrtf(var + BN_EPS) * gamma[f0];
        float y    = (bflo(u) - mean) * sc + beta[f0];
        o.x = (y >= 0.f) ? y : av * y;
    }
    {
        int f1 = f0 + 1;
        float mean = sums[f1] * invN;
        float var  = sums[128 + f1] * invN - mean * mean;
        float sc   = rsqrtf(var + BN_EPS) * gamma[f1];
        float y    = (bfhi(u) - mean) * sc + beta[f1];
        o.y = (y >= 0.f) ? y : av * y;
    }
    ((float2*)out)[idx] = o;
}

// ---------------------------------------------------------------------------
extern "C" void kernel_launch(void* const* d_in, const int* in_sizes, int n_in,
                              void* d_out, int out_size, void* d_ws, size_t ws_size,
                              hipStream_t stream) {
    const float* x      = (const float*)d_in[0];
    const int*   edges  = (const int*)d_in[1];   // [2, E]: src then dst
    const float* W1     = (const float*)d_in[2];
    // b1 = d_in[3] cancels under training-mode BN -> skipped
    const float* gamma1 = (const float*)d_in[4];
    const float* beta1  = (const float*)d_in[5];
    const float* a1     = (const float*)d_in[6];
    const float* W2     = (const float*)d_in[7];
    // b2 = d_in[8] skipped (same reason)
    const float* gamma2 = (const float*)d_in[9];
    const float* beta2  = (const float*)d_in[10];
    const float* a2     = (const float*)d_in[11];

    const int* src = edges;
    const int* dst = edges + N_EDGES;

    float* OUT = (float*)d_out;                      // final f32 output
    char* ws = (char*)d_ws;
    u16*   Abf      = (u16*)ws;    ws += (size_t)N_NODES * D * sizeof(u16);   // 12.8 MB
    u16*   Obf      = (u16*)ws;    ws += (size_t)N_NODES * D * sizeof(u16);   // 12.8 MB
    float* dinv     = (float*)ws;  ws += N_NODES * sizeof(float);
    float* sums     = (float*)ws;  ws += 512 * sizeof(float);   // [0..255]=L1, [256..511]=L2
    int*   row_ptr  = (int*)ws;    ws += (N_NODES + 1) * sizeof(int);
    int*   btot     = (int*)ws;    ws += NB * sizeof(int);
    int*   bbase    = (int*)ws;    ws += NB * sizeof(int);
    int*   thist    = (int*)ws;    ws += (size_t)NTILES * 256 * sizeof(int);  // 200 KB
    unsigned int* brec = (unsigned int*)ws; ws += (size_t)N_EDGES * sizeof(unsigned int);
    u16*   col      = (u16*)ws;    ws += (size_t)N_EDGES * sizeof(u16);
    u16*   Wt1      = (u16*)ws;    ws += 16384 * sizeof(u16);
    u16*   Wt2      = (u16*)ws;    ws += 16384 * sizeof(u16);

    const float invN = 1.0f / (float)N_NODES;
    const int gemmGrid = (N_NODES + GEMM_ROWS - 1) / GEMM_ROWS;   // 391
    const int prGrid   = (N_NODES * 64 + 255) / 256;              // 12500

    // --- hist + weight prep + sums zero ---
    hist_prep<<<NTILES + 128, 256, 0, stream>>>(dst, W1, W2, thist, Wt1, Wt2, sums);

    // --- fused: deterministic bucket scatter + GEMM1 ---
    scatter_gemm1<<<NTILES + gemmGrid, 256, 0, stream>>>(src, dst, thist, brec,
                                                         btot, bbase, row_ptr,
                                                         x, Wt1, Abf);
    bucket_csr<<<NB, 256, 0, stream>>>(brec, bbase, btot, row_ptr, col, dinv);

    // --- layer 1 aggregate (+ fused deterministic BN reduce into sums[0..255]) ---
    pull_agg_bn<<<2048, 256, 0, stream>>>(Abf, row_ptr, col, dinv, Obf, sums);

    // --- layer 2 (BN1+PReLU fused into GEMM2 staging) ---
    gemm2_k<<<gemmGrid, 256, 0, stream>>>(Obf, Wt2, Abf, sums, gamma1, beta1, a1);
    pull_agg_bn<<<2048, 256, 0, stream>>>(Abf, row_ptr, col, dinv, Obf, sums + 256);
    bn_prelu_bf<<<prGrid, 256, 0, stream>>>(Obf, sums + 256, gamma2, beta2, a2, OUT, invN);
}